// Round 14
// baseline (70.632 us; speedup 1.0000x reference)
//
#include <hip/hip_runtime.h>

typedef unsigned short u16;
typedef unsigned int u32;
typedef __attribute__((ext_vector_type(8))) short bfrag;   // 8 x bf16 (4 VGPRs)
typedef __attribute__((ext_vector_type(4))) float f32x4;

#define S_LEN 2048
#define DMODEL 1024
#define NHQ 16
#define NHKV 4
#define HD 64
#define HALFW 128
#define ROWS 4096   // B*S
#define QSCALE 0.1803368801111244f   // 0.125 * log2(e)

__device__ __forceinline__ u16 f2b(float f) {
  u32 x = __float_as_uint(f);
  return (u16)((x + 0x7fffu + ((x >> 16) & 1u)) >> 16);  // RNE
}

__device__ __forceinline__ u32 cvtpk(float lo, float hi) {
  u32 r;
  asm("v_cvt_pk_bf16_f32 %0, %1, %2" : "=v"(r) : "v"(lo), "v"(hi));
  return r;
}

__device__ __forceinline__ float fexp(float x) {  // 2^x
  float r;
  asm("v_exp_f32 %0, %1" : "=v"(r) : "v"(x));
  return r;
}

// ---------------- kernel 1: prep — weights transpose-cast + RoPE table + x cast ----------------
__global__ void prep_k(const float* __restrict__ x, const float* __restrict__ Wq,
                       const float* __restrict__ Wk, const float* __restrict__ Wv,
                       const float* __restrict__ Wo, u16* __restrict__ xb,
                       u16* __restrict__ Wcat_t, u16* __restrict__ Wo_t,
                       float2* __restrict__ csT) {
  __shared__ float tile[32][33];
  int y = blockIdx.y;
  int tid = threadIdx.y * 32 + threadIdx.x;
  if (y >= 88) {  // cast x -> bf16
    int i = (((y - 88) * 32 + blockIdx.x) * 256 + tid) * 4;
    float4 v = *reinterpret_cast<const float4*>(x + i);
    uint2 p;
    p.x = (u32)f2b(v.x) | ((u32)f2b(v.y) << 16);
    p.y = (u32)f2b(v.z) | ((u32)f2b(v.w) << 16);
    *reinterpret_cast<uint2*>(xb + i) = p;
    return;
  }
  if (y >= 80) {  // RoPE table
    int idx = ((y - 80) * 32 + blockIdx.x) * 256 + tid;
    int s = idx >> 5, i = idx & 31;
    double inv = pow(10000.0, -(double)(2 * i) / 64.0);
    double ang = (double)s * inv;
    csT[idx] = make_float2((float)cos(ang), (float)sin(ang));
    return;
  }
  int k0 = blockIdx.x * 32;
  const float* src; u16* dst; int ncols, n0;
  if (y < 32)      { src = Wq; dst = Wcat_t;                       ncols = 1024; n0 = y * 32; }
  else if (y < 40) { src = Wk; dst = Wcat_t + (size_t)1024 * 1024; ncols = 256;  n0 = (y - 32) * 32; }
  else if (y < 48) { src = Wv; dst = Wcat_t + (size_t)1280 * 1024; ncols = 256;  n0 = (y - 40) * 32; }
  else             { src = Wo; dst = Wo_t;                         ncols = 1024; n0 = (y - 48) * 32; }
  int tx = threadIdx.x, ty = threadIdx.y;  // 32 x 8
#pragma unroll
  for (int j = 0; j < 4; ++j)
    tile[ty + 8 * j][tx] = src[(size_t)(k0 + ty + 8 * j) * ncols + n0 + tx];
  __syncthreads();
#pragma unroll
  for (int j = 0; j < 4; ++j)
    dst[(size_t)(n0 + ty + 8 * j) * 1024 + k0 + tx] = f2b(tile[tx][ty + 8 * j]);
}

// ======== GEMM core (R6 proven): 128x64 tile, 4 waves (2x2), BK=64, dbuf, XOR swizzle ========
__device__ __forceinline__ void gemm_core(const u16* __restrict__ A, const u16* __restrict__ Bt,
                                          int m0, int n0, int wave, int lane,
                                          f32x4 acc[4][2]) {
  __shared__ u16 lds_a[2 * 128 * 64];
  __shared__ u16 lds_b[2 * 64 * 64];
  int t = wave * 64 + lane;
  int g = lane >> 4, col = lane & 15;
  int wm = wave >> 1, wn = wave & 1;
  int r8 = t >> 3, slot = (t & 7) ^ (r8 & 7);
  const u16* Ab = A + (size_t)(m0 + r8) * 1024 + slot * 8;
  const u16* Bb = Bt + (size_t)(n0 + r8) * 1024 + slot * 8;
  int c7 = col & 7;
  int aoff0 = (wm * 64 + col) * 64;
  int boff0 = (wn * 32 + col) * 64;
#pragma unroll
  for (int j = 0; j < 4; ++j)
    __builtin_amdgcn_global_load_lds(
        (const __attribute__((address_space(1))) u32*)(Ab + (size_t)j * 32768),
        (__attribute__((address_space(3))) u32*)(lds_a + j * 2048 + wave * 512), 16, 0, 0);
#pragma unroll
  for (int j = 0; j < 2; ++j)
    __builtin_amdgcn_global_load_lds(
        (const __attribute__((address_space(1))) u32*)(Bb + (size_t)j * 32768),
        (__attribute__((address_space(3))) u32*)(lds_b + j * 2048 + wave * 512), 16, 0, 0);
  __syncthreads();
  for (int kt = 0; kt < 16; ++kt) {
    int cur = kt & 1;
    if (kt < 15) {
      int ko = (kt + 1) * 64;
      u16* la = lds_a + (cur ^ 1) * 8192;
      u16* lb = lds_b + (cur ^ 1) * 4096;
#pragma unroll
      for (int j = 0; j < 4; ++j)
        __builtin_amdgcn_global_load_lds(
            (const __attribute__((address_space(1))) u32*)(Ab + (size_t)j * 32768 + ko),
            (__attribute__((address_space(3))) u32*)(la + j * 2048 + wave * 512), 16, 0, 0);
#pragma unroll
      for (int j = 0; j < 2; ++j)
        __builtin_amdgcn_global_load_lds(
            (const __attribute__((address_space(1))) u32*)(Bb + (size_t)j * 32768 + ko),
            (__attribute__((address_space(3))) u32*)(lb + j * 2048 + wave * 512), 16, 0, 0);
    }
    const u16* la = lds_a + cur * 8192;
    const u16* lb = lds_b + cur * 4096;
#pragma unroll
    for (int sub = 0; sub < 2; ++sub) {
      int sa = ((sub * 4 + g) ^ c7) * 8;
      bfrag af[4], bf[2];
#pragma unroll
      for (int mi = 0; mi < 4; ++mi)
        af[mi] = *reinterpret_cast<const bfrag*>(&la[aoff0 + mi * 1024 + sa]);
#pragma unroll
      for (int ni = 0; ni < 2; ++ni)
        bf[ni] = *reinterpret_cast<const bfrag*>(&lb[boff0 + ni * 1024 + sa]);
#pragma unroll
      for (int mi = 0; mi < 4; ++mi)
#pragma unroll
        for (int ni = 0; ni < 2; ++ni)
          acc[mi][ni] = __builtin_amdgcn_mfma_f32_16x16x32_bf16(af[mi], bf[ni], acc[mi][ni], 0, 0, 0);
    }
    if (kt < 15) __syncthreads();
  }
}

// ---------------- kernel 2: QKV GEMM + fused RoPE/scatter epilogue ----------------
__global__ __launch_bounds__(256) void gemm_qkv_k(const u16* __restrict__ A, const u16* __restrict__ Bt,
                                                  const float2* __restrict__ csT,
                                                  u16* __restrict__ Qr, u16* __restrict__ Kr,
                                                  u16* __restrict__ Vt) {
  int t = threadIdx.x;
  int wave = t >> 6, lane = t & 63;
  int g = lane >> 4, col = lane & 15;
  int m0 = blockIdx.y * 128, n0 = blockIdx.x * 64;
  int wm = wave >> 1, wn = wave & 1;
  f32x4 acc[4][2] = {};
  gemm_core(A, Bt, m0, n0, wave, lane, acc);
  bool odd = (col & 1) != 0;
#pragma unroll
  for (int mi = 0; mi < 4; ++mi)
#pragma unroll
    for (int ni = 0; ni < 2; ++ni) {
      int cg = n0 + wn * 32 + ni * 16 + col;
      int rowbase = m0 + wm * 64 + mi * 16 + g * 4;
      if (cg < 1024) {  // Q: RoPE + QSCALE
        int hq = cg >> 6, d = cg & 63, i = d >> 1;
        u16* dst = Qr + ((size_t)((rowbase >> 11) * NHQ + hq) * S_LEN + (rowbase & 2047)) * HD + d;
#pragma unroll
        for (int r = 0; r < 4; ++r) {
          int s = (rowbase + r) & 2047;
          float v = acc[mi][ni][r];
          float pv = __shfl_xor(v, 1);
          float2 cs = csT[s * 32 + i];
          float o = odd ? (pv * cs.y + v * cs.x) : (v * cs.x - pv * cs.y);
          dst[(size_t)r * HD] = f2b(o * QSCALE);
        }
      } else if (cg < 1280) {  // K: RoPE
        int j = cg - 1024;
        int kh = j >> 6, d = j & 63, i = d >> 1;
        u16* dst = Kr + ((size_t)((rowbase >> 11) * NHKV + kh) * S_LEN + (rowbase & 2047)) * HD + d;
#pragma unroll
        for (int r = 0; r < 4; ++r) {
          int s = (rowbase + r) & 2047;
          float v = acc[mi][ni][r];
          float pv = __shfl_xor(v, 1);
          float2 cs = csT[s * 32 + i];
          float o = odd ? (pv * cs.y + v * cs.x) : (v * cs.x - pv * cs.y);
          dst[(size_t)r * HD] = f2b(o);
        }
      } else {  // V: transpose to (b,kv,64,S)
        int j = cg - 1280;
        int kh = j >> 6, d = j & 63;
        int b = rowbase >> 11, s0 = rowbase & 2047;
        uint2 o;
        o.x = (u32)f2b(acc[mi][ni][0]) | ((u32)f2b(acc[mi][ni][1]) << 16);
        o.y = (u32)f2b(acc[mi][ni][2]) | ((u32)f2b(acc[mi][ni][3]) << 16);
        *reinterpret_cast<uint2*>(Vt + ((size_t)(b * NHKV + kh) * HD + d) * S_LEN + s0) = o;
      }
    }
}

// ---------------- kernel 3: out-proj GEMM, C fp32 ----------------
__global__ __launch_bounds__(256) void gemm_bt_k(const u16* __restrict__ A, const u16* __restrict__ Bt,
                                                 float* __restrict__ C, int N) {
  int t = threadIdx.x;
  int wave = t >> 6, lane = t & 63;
  int g = lane >> 4, col = lane & 15;
  int m0 = blockIdx.y * 128, n0 = blockIdx.x * 64;
  int wm = wave >> 1, wn = wave & 1;
  f32x4 acc[4][2] = {};
  gemm_core(A, Bt, m0, n0, wave, lane, acc);
#pragma unroll
  for (int mi = 0; mi < 4; ++mi)
#pragma unroll
    for (int ni = 0; ni < 2; ++ni) {
      int row = m0 + wm * 64 + mi * 16 + g * 4;
      int cc = n0 + wn * 32 + ni * 16 + col;
#pragma unroll
      for (int r = 0; r < 4; ++r)
        C[(size_t)(row + r) * N + cc] = acc[mi][ni][r];
    }
}

// ---------------- kernel 4: sliding-window flash attention ----------------
// 16 q-rows/wave + GQA-shared K/V LDS: block = 4 waves = the 4 q-heads of one kv group
// at the SAME 16 q-rows. Grid = B(2)*NHKV(4)*128 qblks = 1024 blocks; LDS ring 32 KB
// -> 4 blocks/CU -> 4 waves/SIMD (2x R13's TLP; attn is latency-chain-bound per R13's
// null barrier result). R10's 16q penalty (doubled GLOBAL traffic) does not apply:
// K/V come from block-shared LDS; per-output-row MFMA/exp/bpermute totals unchanged.
// Pair-ring staging (R13) retained.
__global__ __launch_bounds__(256) void attn_k(const u16* __restrict__ Qr, const u16* __restrict__ Kr,
                                              const u16* __restrict__ Vt, u16* __restrict__ ctx) {
  __shared__ u16 lds_k[4][32 * 64];   // [ringbuf][key][d] swizzled
  __shared__ u16 lds_v[4][64 * 32];   // [ringbuf][d][key] swizzled
  int bid = blockIdx.x;
  int qblk = bid & 127, kv = (bid >> 7) & 3, b = bid >> 9;
  int tid = threadIdx.x;
  int wave = tid >> 6, lane = tid & 63;
  int g = lane >> 4, col = lane & 15;
  int h = kv * 4 + wave;
  int q0 = qblk * 16;
  const u16* Qb = Qr + (size_t)(b * NHQ + h) * S_LEN * HD;
  const u16* Kb = Kr + (size_t)(b * NHKV + kv) * S_LEN * HD;
  const u16* Vb = Vt + (size_t)(b * NHKV + kv) * HD * S_LEN;
  bfrag qf[2];
  qf[0] = *reinterpret_cast<const bfrag*>(&Qb[(size_t)(q0 + col) * HD + 8 * g]);
  qf[1] = *reinterpret_cast<const bfrag*>(&Qb[(size_t)(q0 + col) * HD + 32 + 8 * g]);
  f32x4 octx[4] = {};
  float lacc = 0.f;
  int qi = q0 + col;
  bool hi5 = (tid & 32) != 0;
  int l0b = (col + ((lane >> 4) & 1) * 32) << 2;
  int l1b = l0b + 64;
  int lo = q0 - HALFW; if (lo < 0) lo = 0; lo &= ~31;
  int hi = q0 + 16 + HALFW; if (hi > S_LEN) hi = S_LEN;
  int nt = (hi - lo + 31) >> 5;
  // staging thread map (pre-swizzled global source, linear LDS dest):
  int kr = tid >> 3, ks = (tid & 7) ^ (kr & 7);   // K: row 0..31, slot 0..7
  int vr = tid >> 2, vs = (tid & 3) ^ (vr & 3);   // V: row(d) 0..63, slot 0..3
  const u16* Ksrc = Kb + (size_t)kr * HD + ks * 8;
  const u16* Vsrc = Vb + (size_t)vr * S_LEN + vs * 8;
  int c7 = col & 7, c3 = col & 3;

  auto STAGE = [&](int buf, int c0) {
    __builtin_amdgcn_global_load_lds(
        (const __attribute__((address_space(1))) u32*)(Ksrc + (size_t)c0 * HD),
        (__attribute__((address_space(3))) u32*)(&lds_k[buf][wave * 512]), 16, 0, 0);
    __builtin_amdgcn_global_load_lds(
        (const __attribute__((address_space(1))) u32*)(Vsrc + c0),
        (__attribute__((address_space(3))) u32*)(&lds_v[buf][wave * 512]), 16, 0, 0);
  };
  auto COMPUTE = [&](int buf, int c0) {
    const u16* lk = lds_k[buf];
    const u16* lv = lds_v[buf];
    f32x4 s[2] = {};   // [kt]
    __builtin_amdgcn_s_setprio(1);
#pragma unroll
    for (int kt = 0; kt < 2; ++kt)
#pragma unroll
      for (int dh = 0; dh < 2; ++dh) {
        bfrag kf = *reinterpret_cast<const bfrag*>(
            &lk[(kt * 16 + col) * 64 + (((dh << 2) | g) ^ c7) * 8]);
        s[kt] = __builtin_amdgcn_mfma_f32_16x16x32_bf16(kf, qf[dh], s[kt], 0, 0, 0);
      }
    __builtin_amdgcn_s_setprio(0);
    bool full = (c0 >= q0 + 15 - HALFW) && (c0 + 31 <= q0 + HALFW);
    float p0[4], p1[4];
    if (full) {
#pragma unroll
      for (int r = 0; r < 4; ++r) { p0[r] = fexp(s[0][r]); p1[r] = fexp(s[1][r]); }
    } else {
      int d0 = c0 + 4 * g - qi + HALFW;
#pragma unroll
      for (int r = 0; r < 4; ++r) {
        p0[r] = ((u32)(d0 + r) <= 2u * HALFW) ? fexp(s[0][r]) : 0.f;
        p1[r] = ((u32)(d0 + 16 + r) <= 2u * HALFW) ? fexp(s[1][r]) : 0.f;
      }
    }
    lacc += ((p0[0] + p0[1]) + (p0[2] + p0[3])) + ((p1[0] + p1[1]) + (p1[2] + p1[3]));
    u32 pk0 = cvtpk(p0[0], p0[1]), pk1 = cvtpk(p0[2], p0[3]);
    u32 pk2 = cvtpk(p1[0], p1[1]), pk3 = cvtpk(p1[2], p1[3]);
    u32 a0 = (u32)__builtin_amdgcn_ds_bpermute(l0b, (int)pk0);
    u32 b0 = (u32)__builtin_amdgcn_ds_bpermute(l0b, (int)pk2);
    u32 a1 = (u32)__builtin_amdgcn_ds_bpermute(l0b, (int)pk1);
    u32 b1 = (u32)__builtin_amdgcn_ds_bpermute(l0b, (int)pk3);
    u32 a2 = (u32)__builtin_amdgcn_ds_bpermute(l1b, (int)pk0);
    u32 b2 = (u32)__builtin_amdgcn_ds_bpermute(l1b, (int)pk2);
    u32 a3 = (u32)__builtin_amdgcn_ds_bpermute(l1b, (int)pk1);
    u32 b3 = (u32)__builtin_amdgcn_ds_bpermute(l1b, (int)pk3);
    union { bfrag f; u32 w[4]; } pb;
    pb.w[0] = hi5 ? b0 : a0;
    pb.w[1] = hi5 ? b1 : a1;
    pb.w[2] = hi5 ? b2 : a2;
    pb.w[3] = hi5 ? b3 : a3;
    __builtin_amdgcn_s_setprio(1);
#pragma unroll
    for (int n = 0; n < 4; ++n) {
      bfrag vf = *reinterpret_cast<const bfrag*>(
          &lv[(n * 16 + col) * 32 + (g ^ c3) * 8]);
      octx[n] = __builtin_amdgcn_mfma_f32_16x16x32_bf16(vf, pb.f, octx[n], 0, 0, 0);
    }
    __builtin_amdgcn_s_setprio(0);
  };

  STAGE(0, lo);
  if (nt > 1) STAGE(1, lo + 32);
  __syncthreads();
  for (int i = 0; i < nt; i += 2) {
    if (i + 2 < nt) STAGE((i + 2) & 3, lo + (i + 2) * 32);
    if (i + 3 < nt) STAGE((i + 3) & 3, lo + (i + 3) * 32);
    COMPUTE(i & 3, lo + i * 32);
    if (i + 1 < nt) COMPUTE((i + 1) & 3, lo + (i + 1) * 32);
    if (i + 2 < nt) __syncthreads();
  }
  float l = lacc + __shfl_xor(lacc, 16);
  l += __shfl_xor(l, 32);
  float linv = __builtin_amdgcn_rcpf(l);
  u16* cb = ctx + (size_t)b * S_LEN * DMODEL + (size_t)(q0 + col) * DMODEL + h * HD;
#pragma unroll
  for (int n = 0; n < 4; ++n) {
    uint2 o;
    o.x = cvtpk(octx[n][0] * linv, octx[n][1] * linv);
    o.y = cvtpk(octx[n][2] * linv, octx[n][3] * linv);
    *reinterpret_cast<uint2*>(cb + n * 16 + 4 * g) = o;
  }
}

extern "C" void kernel_launch(void* const* d_in, const int* in_sizes, int n_in,
                              void* d_out, int out_size, void* d_ws, size_t ws_size,
                              hipStream_t stream) {
  (void)in_sizes; (void)n_in; (void)out_size; (void)ws_size;
  const float* x  = (const float*)d_in[0];
  const float* Wq = (const float*)d_in[1];
  const float* Wk = (const float*)d_in[2];
  const float* Wv = (const float*)d_in[3];
  const float* Wo = (const float*)d_in[4];
  char* ws = (char*)d_ws;
  u16*    xb     = (u16*)(ws + 0);          //  8,388,608
  u16*    Wcat_t = (u16*)(ws + 8388608);    //  3,145,728  (1536 x 1024)
  u16*    Wo_t   = (u16*)(ws + 11534336);   //  2,097,152
  u16*    Qr     = (u16*)(ws + 13631488);   //  8,388,608  (b,h,s,64)
  u16*    Kr     = (u16*)(ws + 22020096);   //  2,097,152  (b,kv,s,64)
  u16*    Vt     = (u16*)(ws + 24117248);   //  2,097,152  (b,kv,64,s)
  u16*    ctxb   = (u16*)(ws + 26214400);   //  8,388,608
  float2* csT    = (float2*)(ws + 34603008);//    524,288  -> total 35,127,296 B

  prep_k<<<dim3(32, 216), dim3(32, 8), 0, stream>>>(x, Wq, Wk, Wv, Wo, xb, Wcat_t, Wo_t, csT);
  gemm_qkv_k<<<dim3(24, 32), 256, 0, stream>>>(xb, Wcat_t, csT, Qr, Kr, Vt);
  attn_k<<<1024, 256, 0, stream>>>(Qr, Kr, Vt, ctxb);
  gemm_bt_k<<<dim3(16, 32), 256, 0, stream>>>(ctxb, Wo_t, (float*)d_out, 1024);
}

// Round 15
// 67.131 us; speedup vs baseline: 1.0521x; 1.0521x over previous
//
#include <hip/hip_runtime.h>

typedef unsigned short u16;
typedef unsigned int u32;
typedef __attribute__((ext_vector_type(8))) short bfrag;   // 8 x bf16 (4 VGPRs)
typedef __attribute__((ext_vector_type(4))) float f32x4;

#define S_LEN 2048
#define DMODEL 1024
#define NHQ 16
#define NHKV 4
#define HD 64
#define HALFW 128
#define ROWS 4096   // B*S
#define QSCALE 0.1803368801111244f   // 0.125 * log2(e)

__device__ __forceinline__ u16 f2b(float f) {
  u32 x = __float_as_uint(f);
  return (u16)((x + 0x7fffu + ((x >> 16) & 1u)) >> 16);  // RNE
}

__device__ __forceinline__ u32 cvtpk(float lo, float hi) {
  u32 r;
  asm("v_cvt_pk_bf16_f32 %0, %1, %2" : "=v"(r) : "v"(lo), "v"(hi));
  return r;
}

__device__ __forceinline__ float fexp(float x) {  // 2^x
  float r;
  asm("v_exp_f32 %0, %1" : "=v"(r) : "v"(x));
  return r;
}

// bijective XCD swizzle (nwg % 8 == 0): XCD j (= bid&7 under round-robin dispatch)
// gets the contiguous chunk [j*nwg/8, (j+1)*nwg/8) of logical block ids.
__device__ __forceinline__ int xcd_swz(int bid, int nwg) {
  return (bid & 7) * (nwg >> 3) + (bid >> 3);
}

// ---------------- kernel 1: prep — weights transpose-cast + RoPE table + x cast ----------------
__global__ void prep_k(const float* __restrict__ x, const float* __restrict__ Wq,
                       const float* __restrict__ Wk, const float* __restrict__ Wv,
                       const float* __restrict__ Wo, u16* __restrict__ xb,
                       u16* __restrict__ Wcat_t, u16* __restrict__ Wo_t,
                       float2* __restrict__ csT) {
  __shared__ float tile[32][33];
  int y = blockIdx.y;
  int tid = threadIdx.y * 32 + threadIdx.x;
  if (y >= 88) {  // cast x -> bf16
    int i = (((y - 88) * 32 + blockIdx.x) * 256 + tid) * 4;
    float4 v = *reinterpret_cast<const float4*>(x + i);
    uint2 p;
    p.x = (u32)f2b(v.x) | ((u32)f2b(v.y) << 16);
    p.y = (u32)f2b(v.z) | ((u32)f2b(v.w) << 16);
    *reinterpret_cast<uint2*>(xb + i) = p;
    return;
  }
  if (y >= 80) {  // RoPE table
    int idx = ((y - 80) * 32 + blockIdx.x) * 256 + tid;
    int s = idx >> 5, i = idx & 31;
    double inv = pow(10000.0, -(double)(2 * i) / 64.0);
    double ang = (double)s * inv;
    csT[idx] = make_float2((float)cos(ang), (float)sin(ang));
    return;
  }
  int k0 = blockIdx.x * 32;
  const float* src; u16* dst; int ncols, n0;
  if (y < 32)      { src = Wq; dst = Wcat_t;                       ncols = 1024; n0 = y * 32; }
  else if (y < 40) { src = Wk; dst = Wcat_t + (size_t)1024 * 1024; ncols = 256;  n0 = (y - 32) * 32; }
  else if (y < 48) { src = Wv; dst = Wcat_t + (size_t)1280 * 1024; ncols = 256;  n0 = (y - 40) * 32; }
  else             { src = Wo; dst = Wo_t;                         ncols = 1024; n0 = (y - 48) * 32; }
  int tx = threadIdx.x, ty = threadIdx.y;  // 32 x 8
#pragma unroll
  for (int j = 0; j < 4; ++j)
    tile[ty + 8 * j][tx] = src[(size_t)(k0 + ty + 8 * j) * ncols + n0 + tx];
  __syncthreads();
#pragma unroll
  for (int j = 0; j < 4; ++j)
    dst[(size_t)(n0 + ty + 8 * j) * 1024 + k0 + tx] = f2b(tile[tx][ty + 8 * j]);
}

// ======== GEMM core (R6 proven): 128x64 tile, 4 waves (2x2), BK=64, dbuf, XOR swizzle ========
__device__ __forceinline__ void gemm_core(const u16* __restrict__ A, const u16* __restrict__ Bt,
                                          int m0, int n0, int wave, int lane,
                                          f32x4 acc[4][2]) {
  __shared__ u16 lds_a[2 * 128 * 64];
  __shared__ u16 lds_b[2 * 64 * 64];
  int t = wave * 64 + lane;
  int g = lane >> 4, col = lane & 15;
  int wm = wave >> 1, wn = wave & 1;
  int r8 = t >> 3, slot = (t & 7) ^ (r8 & 7);
  const u16* Ab = A + (size_t)(m0 + r8) * 1024 + slot * 8;
  const u16* Bb = Bt + (size_t)(n0 + r8) * 1024 + slot * 8;
  int c7 = col & 7;
  int aoff0 = (wm * 64 + col) * 64;
  int boff0 = (wn * 32 + col) * 64;
#pragma unroll
  for (int j = 0; j < 4; ++j)
    __builtin_amdgcn_global_load_lds(
        (const __attribute__((address_space(1))) u32*)(Ab + (size_t)j * 32768),
        (__attribute__((address_space(3))) u32*)(lds_a + j * 2048 + wave * 512), 16, 0, 0);
#pragma unroll
  for (int j = 0; j < 2; ++j)
    __builtin_amdgcn_global_load_lds(
        (const __attribute__((address_space(1))) u32*)(Bb + (size_t)j * 32768),
        (__attribute__((address_space(3))) u32*)(lds_b + j * 2048 + wave * 512), 16, 0, 0);
  __syncthreads();
  for (int kt = 0; kt < 16; ++kt) {
    int cur = kt & 1;
    if (kt < 15) {
      int ko = (kt + 1) * 64;
      u16* la = lds_a + (cur ^ 1) * 8192;
      u16* lb = lds_b + (cur ^ 1) * 4096;
#pragma unroll
      for (int j = 0; j < 4; ++j)
        __builtin_amdgcn_global_load_lds(
            (const __attribute__((address_space(1))) u32*)(Ab + (size_t)j * 32768 + ko),
            (__attribute__((address_space(3))) u32*)(la + j * 2048 + wave * 512), 16, 0, 0);
#pragma unroll
      for (int j = 0; j < 2; ++j)
        __builtin_amdgcn_global_load_lds(
            (const __attribute__((address_space(1))) u32*)(Bb + (size_t)j * 32768 + ko),
            (__attribute__((address_space(3))) u32*)(lb + j * 2048 + wave * 512), 16, 0, 0);
    }
    const u16* la = lds_a + cur * 8192;
    const u16* lb = lds_b + cur * 4096;
#pragma unroll
    for (int sub = 0; sub < 2; ++sub) {
      int sa = ((sub * 4 + g) ^ c7) * 8;
      bfrag af[4], bf[2];
#pragma unroll
      for (int mi = 0; mi < 4; ++mi)
        af[mi] = *reinterpret_cast<const bfrag*>(&la[aoff0 + mi * 1024 + sa]);
#pragma unroll
      for (int ni = 0; ni < 2; ++ni)
        bf[ni] = *reinterpret_cast<const bfrag*>(&lb[boff0 + ni * 1024 + sa]);
#pragma unroll
      for (int mi = 0; mi < 4; ++mi)
#pragma unroll
        for (int ni = 0; ni < 2; ++ni)
          acc[mi][ni] = __builtin_amdgcn_mfma_f32_16x16x32_bf16(af[mi], bf[ni], acc[mi][ni], 0, 0, 0);
    }
    if (kt < 15) __syncthreads();
  }
}

// ---------------- kernel 2: QKV GEMM + fused RoPE/scatter epilogue ----------------
// 1D grid 768 with chunked XCD swizzle: each XCD owns 4 contiguous m-panels (A-panel
// L2 locality); B (weights, 3 MB) is L2-resident per XCD regardless.
__global__ __launch_bounds__(256) void gemm_qkv_k(const u16* __restrict__ A, const u16* __restrict__ Bt,
                                                  const float2* __restrict__ csT,
                                                  u16* __restrict__ Qr, u16* __restrict__ Kr,
                                                  u16* __restrict__ Vt) {
  int t = threadIdx.x;
  int wave = t >> 6, lane = t & 63;
  int g = lane >> 4, col = lane & 15;
  int swz = xcd_swz(blockIdx.x, 768);
  int bx = swz % 24, by = swz / 24;
  int m0 = by * 128, n0 = bx * 64;
  int wm = wave >> 1, wn = wave & 1;
  f32x4 acc[4][2] = {};
  gemm_core(A, Bt, m0, n0, wave, lane, acc);
  bool odd = (col & 1) != 0;
#pragma unroll
  for (int mi = 0; mi < 4; ++mi)
#pragma unroll
    for (int ni = 0; ni < 2; ++ni) {
      int cg = n0 + wn * 32 + ni * 16 + col;
      int rowbase = m0 + wm * 64 + mi * 16 + g * 4;
      if (cg < 1024) {  // Q: RoPE + QSCALE
        int hq = cg >> 6, d = cg & 63, i = d >> 1;
        u16* dst = Qr + ((size_t)((rowbase >> 11) * NHQ + hq) * S_LEN + (rowbase & 2047)) * HD + d;
#pragma unroll
        for (int r = 0; r < 4; ++r) {
          int s = (rowbase + r) & 2047;
          float v = acc[mi][ni][r];
          float pv = __shfl_xor(v, 1);
          float2 cs = csT[s * 32 + i];
          float o = odd ? (pv * cs.y + v * cs.x) : (v * cs.x - pv * cs.y);
          dst[(size_t)r * HD] = f2b(o * QSCALE);
        }
      } else if (cg < 1280) {  // K: RoPE
        int j = cg - 1024;
        int kh = j >> 6, d = j & 63, i = d >> 1;
        u16* dst = Kr + ((size_t)((rowbase >> 11) * NHKV + kh) * S_LEN + (rowbase & 2047)) * HD + d;
#pragma unroll
        for (int r = 0; r < 4; ++r) {
          int s = (rowbase + r) & 2047;
          float v = acc[mi][ni][r];
          float pv = __shfl_xor(v, 1);
          float2 cs = csT[s * 32 + i];
          float o = odd ? (pv * cs.y + v * cs.x) : (v * cs.x - pv * cs.y);
          dst[(size_t)r * HD] = f2b(o);
        }
      } else {  // V: transpose to (b,kv,64,S)
        int j = cg - 1280;
        int kh = j >> 6, d = j & 63;
        int b = rowbase >> 11, s0 = rowbase & 2047;
        uint2 o;
        o.x = (u32)f2b(acc[mi][ni][0]) | ((u32)f2b(acc[mi][ni][1]) << 16);
        o.y = (u32)f2b(acc[mi][ni][2]) | ((u32)f2b(acc[mi][ni][3]) << 16);
        *reinterpret_cast<uint2*>(Vt + ((size_t)(b * NHKV + kh) * HD + d) * S_LEN + s0) = o;
      }
    }
}

// ---------------- kernel 3: out-proj GEMM, C fp32 (1D grid 512, XCD swizzle) ----------------
__global__ __launch_bounds__(256) void gemm_bt_k(const u16* __restrict__ A, const u16* __restrict__ Bt,
                                                 float* __restrict__ C) {
  int t = threadIdx.x;
  int wave = t >> 6, lane = t & 63;
  int g = lane >> 4, col = lane & 15;
  int swz = xcd_swz(blockIdx.x, 512);
  int bx = swz & 15, by = swz >> 4;   // 16 n-blocks x 32 m-blocks
  int m0 = by * 128, n0 = bx * 64;
  int wm = wave >> 1, wn = wave & 1;
  f32x4 acc[4][2] = {};
  gemm_core(A, Bt, m0, n0, wave, lane, acc);
#pragma unroll
  for (int mi = 0; mi < 4; ++mi)
#pragma unroll
    for (int ni = 0; ni < 2; ++ni) {
      int row = m0 + wm * 64 + mi * 16 + g * 4;
      int cc = n0 + wn * 32 + ni * 16 + col;
#pragma unroll
      for (int r = 0; r < 4; ++r)
        C[(size_t)(row + r) * 1024 + cc] = acc[mi][ni][r];
    }
}

// ---------------- kernel 4: sliding-window flash attention (R13 proven config) ----------------
// Block = 4 waves = the 4 q-heads of ONE kv group at the SAME 32 q-rows; K/V staged once
// per block into a 4-buffer LDS ring, tiles processed in pairs. Grid = 2*4*64 = 512.
__global__ __launch_bounds__(256) void attn_k(const u16* __restrict__ Qr, const u16* __restrict__ Kr,
                                              const u16* __restrict__ Vt, u16* __restrict__ ctx) {
  __shared__ u16 lds_k[4][32 * 64];   // [ringbuf][key][d] swizzled
  __shared__ u16 lds_v[4][64 * 32];   // [ringbuf][d][key] swizzled
  int bid = blockIdx.x;
  int qblk = bid & 63, kv = (bid >> 6) & 3, b = bid >> 8;
  int tid = threadIdx.x;
  int wave = tid >> 6, lane = tid & 63;
  int g = lane >> 4, col = lane & 15;
  int h = kv * 4 + wave;
  int q0 = qblk * 32;
  const u16* Qb = Qr + (size_t)(b * NHQ + h) * S_LEN * HD;
  const u16* Kb = Kr + (size_t)(b * NHKV + kv) * S_LEN * HD;
  const u16* Vb = Vt + (size_t)(b * NHKV + kv) * HD * S_LEN;
  bfrag qf[2][2];
#pragma unroll
  for (int qg = 0; qg < 2; ++qg) {
    qf[qg][0] = *reinterpret_cast<const bfrag*>(&Qb[(size_t)(q0 + qg * 16 + col) * HD + 8 * g]);
    qf[qg][1] = *reinterpret_cast<const bfrag*>(&Qb[(size_t)(q0 + qg * 16 + col) * HD + 32 + 8 * g]);
  }
  f32x4 octx[2][4] = {};
  float lacc[2] = {0.f, 0.f};
  int qi[2] = {q0 + col, q0 + 16 + col};
  bool hi5 = (tid & 32) != 0;
  int l0b = (col + ((lane >> 4) & 1) * 32) << 2;
  int l1b = l0b + 64;
  int lo = q0 - HALFW; if (lo < 0) lo = 0; lo &= ~31;
  int hi = q0 + 32 + HALFW; if (hi > S_LEN) hi = S_LEN;
  int nt = (hi - lo) >> 5;
  // staging thread map (pre-swizzled global source, linear LDS dest):
  int kr = tid >> 3, ks = (tid & 7) ^ (kr & 7);   // K: row 0..31, slot 0..7
  int vr = tid >> 2, vs = (tid & 3) ^ (vr & 3);   // V: row(d) 0..63, slot 0..3
  const u16* Ksrc = Kb + (size_t)kr * HD + ks * 8;
  const u16* Vsrc = Vb + (size_t)vr * S_LEN + vs * 8;
  int c7 = col & 7, c3 = col & 3;

  auto STAGE = [&](int buf, int c0) {
    __builtin_amdgcn_global_load_lds(
        (const __attribute__((address_space(1))) u32*)(Ksrc + (size_t)c0 * HD),
        (__attribute__((address_space(3))) u32*)(&lds_k[buf][wave * 512]), 16, 0, 0);
    __builtin_amdgcn_global_load_lds(
        (const __attribute__((address_space(1))) u32*)(Vsrc + c0),
        (__attribute__((address_space(3))) u32*)(&lds_v[buf][wave * 512]), 16, 0, 0);
  };
  auto COMPUTE = [&](int buf, int c0) {
    const u16* lk = lds_k[buf];
    const u16* lv = lds_v[buf];
    f32x4 s[2][2] = {};   // [qg][kt]
    __builtin_amdgcn_s_setprio(1);
#pragma unroll
    for (int kt = 0; kt < 2; ++kt)
#pragma unroll
      for (int dh = 0; dh < 2; ++dh) {
        bfrag kf = *reinterpret_cast<const bfrag*>(
            &lk[(kt * 16 + col) * 64 + (((dh << 2) | g) ^ c7) * 8]);
        s[0][kt] = __builtin_amdgcn_mfma_f32_16x16x32_bf16(kf, qf[0][dh], s[0][kt], 0, 0, 0);
        s[1][kt] = __builtin_amdgcn_mfma_f32_16x16x32_bf16(kf, qf[1][dh], s[1][kt], 0, 0, 0);
      }
    __builtin_amdgcn_s_setprio(0);
    bool full = (c0 >= q0 + 31 - HALFW) && (c0 + 31 <= q0 + HALFW);
    union { bfrag f; u32 w[4]; } pb[2];
#pragma unroll
    for (int qg = 0; qg < 2; ++qg) {
      float p0[4], p1[4];
      if (full) {
#pragma unroll
        for (int r = 0; r < 4; ++r) { p0[r] = fexp(s[qg][0][r]); p1[r] = fexp(s[qg][1][r]); }
      } else {
        int d0 = c0 + 4 * g - qi[qg] + HALFW;
#pragma unroll
        for (int r = 0; r < 4; ++r) {
          p0[r] = ((u32)(d0 + r) <= 2u * HALFW) ? fexp(s[qg][0][r]) : 0.f;
          p1[r] = ((u32)(d0 + 16 + r) <= 2u * HALFW) ? fexp(s[qg][1][r]) : 0.f;
        }
      }
      lacc[qg] += ((p0[0] + p0[1]) + (p0[2] + p0[3])) + ((p1[0] + p1[1]) + (p1[2] + p1[3]));
      u32 pk0 = cvtpk(p0[0], p0[1]), pk1 = cvtpk(p0[2], p0[3]);
      u32 pk2 = cvtpk(p1[0], p1[1]), pk3 = cvtpk(p1[2], p1[3]);
      u32 a0 = (u32)__builtin_amdgcn_ds_bpermute(l0b, (int)pk0);
      u32 b0 = (u32)__builtin_amdgcn_ds_bpermute(l0b, (int)pk2);
      u32 a1 = (u32)__builtin_amdgcn_ds_bpermute(l0b, (int)pk1);
      u32 b1 = (u32)__builtin_amdgcn_ds_bpermute(l0b, (int)pk3);
      u32 a2 = (u32)__builtin_amdgcn_ds_bpermute(l1b, (int)pk0);
      u32 b2 = (u32)__builtin_amdgcn_ds_bpermute(l1b, (int)pk2);
      u32 a3 = (u32)__builtin_amdgcn_ds_bpermute(l1b, (int)pk1);
      u32 b3 = (u32)__builtin_amdgcn_ds_bpermute(l1b, (int)pk3);
      pb[qg].w[0] = hi5 ? b0 : a0;
      pb[qg].w[1] = hi5 ? b1 : a1;
      pb[qg].w[2] = hi5 ? b2 : a2;
      pb[qg].w[3] = hi5 ? b3 : a3;
    }
    __builtin_amdgcn_s_setprio(1);
#pragma unroll
    for (int n = 0; n < 4; ++n) {
      bfrag vf = *reinterpret_cast<const bfrag*>(
          &lv[(n * 16 + col) * 32 + (g ^ c3) * 8]);
      octx[0][n] = __builtin_amdgcn_mfma_f32_16x16x32_bf16(vf, pb[0].f, octx[0][n], 0, 0, 0);
      octx[1][n] = __builtin_amdgcn_mfma_f32_16x16x32_bf16(vf, pb[1].f, octx[1][n], 0, 0, 0);
    }
    __builtin_amdgcn_s_setprio(0);
  };

  STAGE(0, lo);
  if (nt > 1) STAGE(1, lo + 32);
  __syncthreads();
  for (int i = 0; i < nt; i += 2) {
    if (i + 2 < nt) STAGE((i + 2) & 3, lo + (i + 2) * 32);
    if (i + 3 < nt) STAGE((i + 3) & 3, lo + (i + 3) * 32);
    COMPUTE(i & 3, lo + i * 32);
    if (i + 1 < nt) COMPUTE((i + 1) & 3, lo + (i + 1) * 32);
    if (i + 2 < nt) __syncthreads();
  }
#pragma unroll
  for (int qg = 0; qg < 2; ++qg) {
    float l = lacc[qg] + __shfl_xor(lacc[qg], 16);
    l += __shfl_xor(l, 32);
    float linv = __builtin_amdgcn_rcpf(l);
    u16* cb = ctx + (size_t)b * S_LEN * DMODEL + (size_t)(q0 + qg * 16 + col) * DMODEL + h * HD;
#pragma unroll
    for (int n = 0; n < 4; ++n) {
      uint2 o;
      o.x = cvtpk(octx[qg][n][0] * linv, octx[qg][n][1] * linv);
      o.y = cvtpk(octx[qg][n][2] * linv, octx[qg][n][3] * linv);
      *reinterpret_cast<uint2*>(cb + n * 16 + 4 * g) = o;
    }
  }
}

extern "C" void kernel_launch(void* const* d_in, const int* in_sizes, int n_in,
                              void* d_out, int out_size, void* d_ws, size_t ws_size,
                              hipStream_t stream) {
  (void)in_sizes; (void)n_in; (void)out_size; (void)ws_size;
  const float* x  = (const float*)d_in[0];
  const float* Wq = (const float*)d_in[1];
  const float* Wk = (const float*)d_in[2];
  const float* Wv = (const float*)d_in[3];
  const float* Wo = (const float*)d_in[4];
  char* ws = (char*)d_ws;
  u16*    xb     = (u16*)(ws + 0);          //  8,388,608
  u16*    Wcat_t = (u16*)(ws + 8388608);    //  3,145,728  (1536 x 1024)
  u16*    Wo_t   = (u16*)(ws + 11534336);   //  2,097,152
  u16*    Qr     = (u16*)(ws + 13631488);   //  8,388,608  (b,h,s,64)
  u16*    Kr     = (u16*)(ws + 22020096);   //  2,097,152  (b,kv,s,64)
  u16*    Vt     = (u16*)(ws + 24117248);   //  2,097,152  (b,kv,64,s)
  u16*    ctxb   = (u16*)(ws + 26214400);   //  8,388,608
  float2* csT    = (float2*)(ws + 34603008);//    524,288  -> total 35,127,296 B

  prep_k<<<dim3(32, 216), dim3(32, 8), 0, stream>>>(x, Wq, Wk, Wv, Wo, xb, Wcat_t, Wo_t, csT);
  gemm_qkv_k<<<768, 256, 0, stream>>>(xb, Wcat_t, csT, Qr, Kr, Vt);
  attn_k<<<512, 256, 0, stream>>>(Qr, Kr, Vt, ctxb);
  gemm_bt_k<<<512, 256, 0, stream>>>(ctxb, Wo_t, (float*)d_out);
}